// Round 1
// baseline (198.866 us; speedup 1.0000x reference)
//
#include <hip/hip_runtime.h>
#include <math.h>

#define N_ 4
#define C_ 256
#define D_ 128
#define S_ 4096
#define LOG2E 1.4426950408889634f

typedef __attribute__((ext_vector_type(4))) float f32x4;
typedef __attribute__((ext_vector_type(8))) short short8;
typedef __attribute__((ext_vector_type(8))) unsigned short ushort8;
typedef __attribute__((ext_vector_type(4))) unsigned short ushort4v;

#define MFMA16(a, b, c) __builtin_amdgcn_mfma_f32_16x16x32_bf16((a), (b), (c), 0, 0, 0)

__device__ __forceinline__ unsigned short f2bf(float f) {
  union { float f; unsigned int u; } v; v.f = f;
  unsigned int r = v.u + 0x7fffu + ((v.u >> 16) & 1u);  // RNE
  return (unsigned short)(r >> 16);
}

__device__ __forceinline__ float redmax16(float v) {
  v = fmaxf(v, __shfl_xor(v, 1));
  v = fmaxf(v, __shfl_xor(v, 2));
  v = fmaxf(v, __shfl_xor(v, 4));
  v = fmaxf(v, __shfl_xor(v, 8));
  return v;
}
__device__ __forceinline__ float redsum16(float v) {
  v += __shfl_xor(v, 1);
  v += __shfl_xor(v, 2);
  v += __shfl_xor(v, 4);
  v += __shfl_xor(v, 8);
  return v;
}

// ---------------- fp32 -> bf16 conversion (8 elems / thread) ----------------
__global__ void k_convert(const float* __restrict__ src, unsigned short* __restrict__ dst, int n8) {
  int i = blockIdx.x * blockDim.x + threadIdx.x;
  if (i >= n8) return;
  const float4* s = reinterpret_cast<const float4*>(src) + (size_t)i * 2;
  float4 a = s[0], b = s[1];
  ushort8 o;
  o[0] = f2bf(a.x); o[1] = f2bf(a.y); o[2] = f2bf(a.z); o[3] = f2bf(a.w);
  o[4] = f2bf(b.x); o[5] = f2bf(b.y); o[6] = f2bf(b.z); o[7] = f2bf(b.w);
  reinterpret_cast<ushort8*>(dst)[i] = o;
}

// ---------------- projections: Q=Wt*x (N,S,D), K=Wp*x (N,S,D), V=Wg*x (N,D,S)
__global__ __launch_bounds__(256, 2) void k_proj(
    const unsigned short* __restrict__ xb,
    const unsigned short* __restrict__ wg, const unsigned short* __restrict__ wt,
    const unsigned short* __restrict__ wp,
    const float* __restrict__ bg, const float* __restrict__ bt, const float* __restrict__ bp,
    unsigned short* __restrict__ qb, unsigned short* __restrict__ kb, unsigned short* __restrict__ vb)
{
  __shared__ __align__(16) unsigned short xs[C_ * 64];  // [c][s], 32 KB
  const int tid = threadIdx.x;
  const int n = blockIdx.x >> 6;
  const int s0 = (blockIdx.x & 63) << 6;
  const unsigned short* xsrc = xb + (size_t)n * C_ * S_ + s0;
#pragma unroll
  for (int i = 0; i < 8; ++i) {
    int flat = i * 256 + tid;               // 2048 16B-chunks
    int c = flat >> 3, s8 = (flat & 7) << 3;
    *reinterpret_cast<ushort8*>(xs + c * 64 + s8) =
        *reinterpret_cast<const ushort8*>(xsrc + (size_t)c * S_ + s8);
  }
  __syncthreads();
  const int lane = tid & 63, wid = tid >> 6;
  const int l15 = lane & 15, g = lane >> 4;
  const int scol = wid * 16 + l15;          // this wave's 16 s-columns

  // B-fragments from X (column gathers, reused across 24 MFMAs each)
  short8 bx[8];
#pragma unroll
  for (int kc = 0; kc < 8; ++kc) {
    int cb = kc * 32 + g * 8;
    short8 t;
#pragma unroll
    for (int j = 0; j < 8; ++j) t[j] = (short)xs[(cb + j) * 64 + scol];
    bx[kc] = t;
  }

  const f32x4 fz = {0.f, 0.f, 0.f, 0.f};
  for (int p = 0; p < 3; ++p) {
    const unsigned short* W = (p == 0) ? wg : ((p == 1) ? wt : wp);
    const float* bias = (p == 0) ? bg : ((p == 1) ? bt : bp);
    f32x4 acc[8];
#pragma unroll
    for (int dt = 0; dt < 8; ++dt) acc[dt] = fz;
#pragma unroll
    for (int dt = 0; dt < 8; ++dt) {
      const unsigned short* wrow = W + (size_t)(dt * 16 + l15) * C_ + g * 8;
#pragma unroll
      for (int kc = 0; kc < 8; ++kc) {
        short8 a = *reinterpret_cast<const short8*>(wrow + kc * 32);
        acc[dt] = MFMA16(a, bx[kc], acc[dt]);
      }
    }
    if (p == 0) {  // V -> (n, d, s)
#pragma unroll
      for (int dt = 0; dt < 8; ++dt) {
#pragma unroll
        for (int r = 0; r < 4; ++r) {
          int d = dt * 16 + 4 * g + r;
          vb[((size_t)n * D_ + d) * S_ + s0 + scol] = f2bf(acc[dt][r] + bias[d]);
        }
      }
    } else {       // Q/K -> (n, s, d), packed 4-bf16 stores
      unsigned short* dst = (p == 1) ? qb : kb;
      unsigned short* row = dst + ((size_t)(n * S_) + s0 + scol) * D_;
#pragma unroll
      for (int dt = 0; dt < 8; ++dt) {
        ushort4v o;
#pragma unroll
        for (int r = 0; r < 4; ++r) {
          int d = dt * 16 + 4 * g + r;
          o[r] = f2bf(acc[dt][r] + bias[d]);
        }
        *reinterpret_cast<ushort4v*>(row + dt * 16 + 4 * g) = o;
      }
    }
  }
}

// ---------------- flash attention: y(n,s,d) = softmax(Q K^T) V ----------------
__global__ __launch_bounds__(256, 2) void k_attn(
    const unsigned short* __restrict__ qb, const unsigned short* __restrict__ kb,
    const unsigned short* __restrict__ vb, unsigned short* __restrict__ yb)
{
  __shared__ __align__(16) unsigned short qs[64 * 128];   // [q][d] swizzled
  __shared__ __align__(16) unsigned short ks[64 * 128];   // [kv][d] swizzled
  __shared__ __align__(16) unsigned short vs[128 * 64];   // [d][kv] swizzled
  __shared__ __align__(16) unsigned short ps[4 * 16 * 64];// per-wave P, swizzled
  const int tid = threadIdx.x, lane = tid & 63, wid = tid >> 6;
  const int l15 = lane & 15, g = lane >> 4;
  const int n = blockIdx.x >> 6, q0 = (blockIdx.x & 63) << 6;

  const unsigned short* qsrc = qb + ((size_t)n * S_ + q0) * D_;
#pragma unroll
  for (int i = 0; i < 4; ++i) {
    int flat = i * 256 + tid;
    int r = flat >> 4, c = flat & 15;
    *reinterpret_cast<ushort8*>(qs + r * 128 + ((c ^ (r & 7)) << 3)) =
        *reinterpret_cast<const ushort8*>(qsrc + r * D_ + c * 8);
  }
  __syncthreads();

  // hoist Q A-fragments (loop-invariant across KV tiles)
  short8 aq[4];
#pragma unroll
  for (int kc = 0; kc < 4; ++kc) {
    int r = wid * 16 + l15;
    int ch = (kc * 4 + g) ^ (r & 7);
    aq[kc] = *reinterpret_cast<const short8*>(qs + r * 128 + ch * 8);
  }

  const f32x4 fz = {0.f, 0.f, 0.f, 0.f};
  float m_[4], l_[4];
  f32x4 acc_o[8];
#pragma unroll
  for (int r = 0; r < 4; ++r) { m_[r] = -3.4e38f; l_[r] = 0.f; }
#pragma unroll
  for (int dt = 0; dt < 8; ++dt) acc_o[dt] = fz;

  const unsigned short* kbase0 = kb + (size_t)n * S_ * D_;
  const unsigned short* vbase0 = vb + (size_t)n * D_ * S_;
  unsigned short* pw = ps + wid * 1024;

  for (int t = 0; t < 64; ++t) {
    __syncthreads();  // all waves done with previous K/V before overwrite
    const unsigned short* kbase = kbase0 + (size_t)t * 64 * D_;
#pragma unroll
    for (int i = 0; i < 4; ++i) {
      int flat = i * 256 + tid;
      int r = flat >> 4, c = flat & 15;
      *reinterpret_cast<ushort8*>(ks + r * 128 + ((c ^ (r & 7)) << 3)) =
          *reinterpret_cast<const ushort8*>(kbase + r * D_ + c * 8);
    }
    const unsigned short* vbase = vbase0 + t * 64;
#pragma unroll
    for (int i = 0; i < 4; ++i) {
      int flat = i * 256 + tid;
      int r = flat >> 3, c = flat & 7;
      *reinterpret_cast<ushort8*>(vs + r * 64 + ((c ^ (r & 7)) << 3)) =
          *reinterpret_cast<const ushort8*>(vbase + (size_t)r * S_ + c * 8);
    }
    __syncthreads();

    // S = Q K^T  (wave's 16 q-rows x 64 kv-cols)
    f32x4 sc[4];
#pragma unroll
    for (int ct = 0; ct < 4; ++ct) {
      f32x4 a4 = fz;
      int r = ct * 16 + l15;
#pragma unroll
      for (int kc = 0; kc < 4; ++kc) {
        int ch = (kc * 4 + g) ^ (r & 7);
        short8 bk = *reinterpret_cast<const short8*>(ks + r * 128 + ch * 8);
        a4 = MFMA16(aq[kc], bk, a4);
      }
      sc[ct] = a4;
    }

    // online softmax (rows r live across lanes sharing g; cols across l15 x ct)
    float mx[4], sscale[4], rs[4];
#pragma unroll
    for (int r = 0; r < 4; ++r) {
      mx[r] = redmax16(fmaxf(fmaxf(sc[0][r], sc[1][r]), fmaxf(sc[2][r], sc[3][r])));
      float mn = fmaxf(m_[r], mx[r]);
      sscale[r] = exp2f((m_[r] - mn) * LOG2E);
      m_[r] = mn;
      rs[r] = 0.f;
    }
#pragma unroll
    for (int ct = 0; ct < 4; ++ct) {
#pragma unroll
      for (int r = 0; r < 4; ++r) {
        float pv = exp2f((sc[ct][r] - m_[r]) * LOG2E);
        sc[ct][r] = pv;
        rs[r] += pv;
      }
    }
#pragma unroll
    for (int r = 0; r < 4; ++r) {
      rs[r] = redsum16(rs[r]);
      l_[r] = l_[r] * sscale[r] + rs[r];
    }
#pragma unroll
    for (int dt = 0; dt < 8; ++dt) {
#pragma unroll
      for (int r = 0; r < 4; ++r) acc_o[dt][r] *= sscale[r];
    }

    // P -> wave-private swizzled LDS (bf16)
#pragma unroll
    for (int ct = 0; ct < 4; ++ct) {
#pragma unroll
      for (int r = 0; r < 4; ++r) {
        int row = 4 * g + r;
        int col = ct * 16 + l15;
        pw[row * 64 + (col ^ ((row & 7) << 3))] = f2bf(sc[ct][r]);
      }
    }
    asm volatile("s_waitcnt lgkmcnt(0)" ::: "memory");  // wave-local P fence

    // O += P V
    short8 ap[2];
#pragma unroll
    for (int kk = 0; kk < 2; ++kk) {
      int ch = (kk * 4 + g) ^ (l15 & 7);
      ap[kk] = *reinterpret_cast<const short8*>(pw + l15 * 64 + ch * 8);
    }
#pragma unroll
    for (int dt = 0; dt < 8; ++dt) {
      int r = dt * 16 + l15;
#pragma unroll
      for (int kk = 0; kk < 2; ++kk) {
        int ch = (kk * 4 + g) ^ (r & 7);
        short8 bv = *reinterpret_cast<const short8*>(vs + r * 64 + ch * 8);
        acc_o[dt] = MFMA16(ap[kk], bv, acc_o[dt]);
      }
    }
  }

  // epilogue: y = O / l  -> (n, s, d) bf16
  unsigned short* ydst = yb + ((size_t)n * S_ + q0 + wid * 16) * D_;
#pragma unroll
  for (int r = 0; r < 4; ++r) l_[r] = 1.f / l_[r];
#pragma unroll
  for (int dt = 0; dt < 8; ++dt) {
#pragma unroll
    for (int r = 0; r < 4; ++r) {
      int row = 4 * g + r;
      ydst[(size_t)row * D_ + dt * 16 + l15] = f2bf(acc_o[dt][r] * l_[r]);
    }
  }
}

// ---------------- out = Wz*y + bz + x  (fp32 out) ----------------
__global__ __launch_bounds__(256, 2) void k_final(
    const unsigned short* __restrict__ yb, const unsigned short* __restrict__ wz,
    const float* __restrict__ bz, const float* __restrict__ x, float* __restrict__ out)
{
  __shared__ __align__(16) unsigned short ysm[64 * 128];  // [s][d] swizzled
  const int tid = threadIdx.x, lane = tid & 63, wid = tid >> 6;
  const int l15 = lane & 15, g = lane >> 4;
  const int n = blockIdx.x >> 6, s0 = (blockIdx.x & 63) << 6;
#pragma unroll
  for (int i = 0; i < 4; ++i) {
    int flat = i * 256 + tid;
    int r = flat >> 4, c = flat & 15;
    *reinterpret_cast<ushort8*>(ysm + r * 128 + ((c ^ (r & 7)) << 3)) =
        *reinterpret_cast<const ushort8*>(yb + ((size_t)n * S_ + s0 + r) * D_ + c * 8);
  }
  __syncthreads();
  const int c0 = wid * 64;
  const f32x4 fz = {0.f, 0.f, 0.f, 0.f};
  f32x4 acc[4][4];
#pragma unroll
  for (int ct = 0; ct < 4; ++ct)
#pragma unroll
    for (int st = 0; st < 4; ++st) acc[ct][st] = fz;
#pragma unroll
  for (int kc = 0; kc < 4; ++kc) {
    short8 by[4];
#pragma unroll
    for (int st = 0; st < 4; ++st) {
      int r = st * 16 + l15;
      int ch = (kc * 4 + g) ^ (r & 7);
      by[st] = *reinterpret_cast<const short8*>(ysm + r * 128 + ch * 8);
    }
#pragma unroll
    for (int ct = 0; ct < 4; ++ct) {
      const short8 aw = *reinterpret_cast<const short8*>(
          wz + (size_t)(c0 + ct * 16 + l15) * D_ + kc * 32 + g * 8);
#pragma unroll
      for (int st = 0; st < 4; ++st) acc[ct][st] = MFMA16(aw, by[st], acc[ct][st]);
    }
  }
#pragma unroll
  for (int ct = 0; ct < 4; ++ct) {
#pragma unroll
    for (int r = 0; r < 4; ++r) {
      int c = c0 + ct * 16 + 4 * g + r;
      float bias = bz[c];
#pragma unroll
      for (int st = 0; st < 4; ++st) {
        int s = s0 + st * 16 + l15;
        size_t idx = ((size_t)(n * C_ + c)) * S_ + s;
        out[idx] = acc[ct][st][r] + bias + x[idx];
      }
    }
  }
}

extern "C" void kernel_launch(void* const* d_in, const int* in_sizes, int n_in,
                              void* d_out, int out_size, void* d_ws, size_t ws_size,
                              hipStream_t stream) {
  const float* x  = (const float*)d_in[0];
  const float* Wg = (const float*)d_in[1];
  const float* bg = (const float*)d_in[2];
  const float* Wt = (const float*)d_in[3];
  const float* bt = (const float*)d_in[4];
  const float* Wp = (const float*)d_in[5];
  const float* bp = (const float*)d_in[6];
  const float* Wz = (const float*)d_in[7];
  const float* bz = (const float*)d_in[8];
  float* out = (float*)d_out;
  char* ws = (char*)d_ws;
  const size_t MB = 1u << 20;
  unsigned short* xb  = (unsigned short*)(ws);             // 8 MB  (N,C,S) bf16
  unsigned short* qb  = (unsigned short*)(ws + 8 * MB);    // 4 MB  (N,S,D)
  unsigned short* kb  = (unsigned short*)(ws + 12 * MB);   // 4 MB  (N,S,D)
  unsigned short* vb  = (unsigned short*)(ws + 16 * MB);   // 4 MB  (N,D,S)
  unsigned short* yb  = (unsigned short*)(ws + 20 * MB);   // 4 MB  (N,S,D)
  unsigned short* wgb = (unsigned short*)(ws + 24 * MB);
  unsigned short* wtb = (unsigned short*)(ws + 24 * MB + 65536);
  unsigned short* wpb = (unsigned short*)(ws + 24 * MB + 131072);
  unsigned short* wzb = (unsigned short*)(ws + 24 * MB + 196608);

  k_convert<<<2048, 256, 0, stream>>>(x,  xb,  524288);
  k_convert<<<16,   256, 0, stream>>>(Wg, wgb, 4096);
  k_convert<<<16,   256, 0, stream>>>(Wt, wtb, 4096);
  k_convert<<<16,   256, 0, stream>>>(Wp, wpb, 4096);
  k_convert<<<16,   256, 0, stream>>>(Wz, wzb, 4096);
  k_proj <<<256, 256, 0, stream>>>(xb, wgb, wtb, wpb, bg, bt, bp, qb, kb, vb);
  k_attn <<<256, 256, 0, stream>>>(qb, kb, vb, yb);
  k_final<<<256, 256, 0, stream>>>(yb, wzb, bz, x, out);
}

// Round 2
// 140.510 us; speedup vs baseline: 1.4153x; 1.4153x over previous
//
#include <hip/hip_runtime.h>
#include <math.h>

#define N_ 4
#define C_ 256
#define D_ 128
#define S_ 4096
#define LOG2E 1.4426950408889634f
#define SPLIT 4
#define TPS 16   // KV tiles per split slice (64 total / SPLIT)

typedef __attribute__((ext_vector_type(4))) float f32x4;
typedef __attribute__((ext_vector_type(8))) short short8;
typedef __attribute__((ext_vector_type(8))) unsigned short ushort8;
typedef __attribute__((ext_vector_type(4))) unsigned short ushort4v;

#define MFMA16(a, b, c) __builtin_amdgcn_mfma_f32_16x16x32_bf16((a), (b), (c), 0, 0, 0)

__device__ __forceinline__ unsigned short f2bf(float f) {
  union { float f; unsigned int u; } v; v.f = f;
  unsigned int r = v.u + 0x7fffu + ((v.u >> 16) & 1u);  // RNE
  return (unsigned short)(r >> 16);
}
__device__ __forceinline__ float bf2f(unsigned short u) {
  union { unsigned int u; float f; } v; v.u = ((unsigned int)u) << 16;
  return v.f;
}
__device__ __forceinline__ float redmax16(float v) {
  v = fmaxf(v, __shfl_xor(v, 1));
  v = fmaxf(v, __shfl_xor(v, 2));
  v = fmaxf(v, __shfl_xor(v, 4));
  v = fmaxf(v, __shfl_xor(v, 8));
  return v;
}
__device__ __forceinline__ float redsum16(float v) {
  v += __shfl_xor(v, 1);
  v += __shfl_xor(v, 2);
  v += __shfl_xor(v, 4);
  v += __shfl_xor(v, 8);
  return v;
}
// async global->LDS, 16B per lane; lds dest must be wave-uniform base (lane-linear fill)
__device__ __forceinline__ void gload16(const void* g, void* l) {
  __builtin_amdgcn_global_load_lds((const __attribute__((address_space(1))) unsigned int*)g,
                                   (__attribute__((address_space(3))) unsigned int*)l,
                                   16, 0, 0);
}

// ---------------- all 4 weight matrices fp32 -> bf16 in one launch ----------------
__global__ void k_convw(const float* __restrict__ w0, const float* __restrict__ w1,
                        const float* __restrict__ w2, const float* __restrict__ w3,
                        unsigned short* __restrict__ d0, unsigned short* __restrict__ d1,
                        unsigned short* __restrict__ d2, unsigned short* __restrict__ d3) {
  int b = blockIdx.x;
  int w = b >> 4;
  int i = (b & 15) * 256 + threadIdx.x;  // 8 elems each, 32768 elems per matrix
  const float* s = (w == 0) ? w0 : (w == 1) ? w1 : (w == 2) ? w2 : w3;
  unsigned short* d = (w == 0) ? d0 : (w == 1) ? d1 : (w == 2) ? d2 : d3;
  const float4* sp = reinterpret_cast<const float4*>(s) + (size_t)i * 2;
  float4 a = sp[0], c = sp[1];
  ushort8 o;
  o[0] = f2bf(a.x); o[1] = f2bf(a.y); o[2] = f2bf(a.z); o[3] = f2bf(a.w);
  o[4] = f2bf(c.x); o[5] = f2bf(c.y); o[6] = f2bf(c.z); o[7] = f2bf(c.w);
  reinterpret_cast<ushort8*>(d)[i] = o;
}

// ---------------- projections: V=Wg*x -> (N,D,S), Q=Wt*x -> (N,S,D), K=Wp*x -> (N,S,D)
// reads x fp32 directly, converts during LDS staging (kills the x-convert pass)
__global__ __launch_bounds__(256, 2) void k_proj(
    const float* __restrict__ x,
    const unsigned short* __restrict__ wg, const unsigned short* __restrict__ wt,
    const unsigned short* __restrict__ wp,
    const float* __restrict__ bg, const float* __restrict__ bt, const float* __restrict__ bp,
    unsigned short* __restrict__ qb, unsigned short* __restrict__ kb, unsigned short* __restrict__ vb)
{
  __shared__ __align__(16) unsigned short xs[C_ * 64];  // [c][s] bf16, 32 KB
  const int tid = threadIdx.x;
  const int n = blockIdx.x >> 6;
  const int s0 = (blockIdx.x & 63) << 6;
  const float* xsrc = x + (size_t)n * C_ * S_ + s0;
#pragma unroll
  for (int i = 0; i < 16; ++i) {
    int ch = i * 256 + tid;                 // 4096 float4-chunks
    int c = ch >> 4, s4 = (ch & 15) << 2;
    float4 v = *reinterpret_cast<const float4*>(xsrc + (size_t)c * S_ + s4);
    ushort4v o;
    o[0] = f2bf(v.x); o[1] = f2bf(v.y); o[2] = f2bf(v.z); o[3] = f2bf(v.w);
    *reinterpret_cast<ushort4v*>(xs + c * 64 + s4) = o;
  }
  __syncthreads();
  const int lane = tid & 63, wid = tid >> 6;
  const int l15 = lane & 15, g = lane >> 4;
  const int scol = wid * 16 + l15;

  short8 bx[8];
#pragma unroll
  for (int kc = 0; kc < 8; ++kc) {
    int cb = kc * 32 + g * 8;
    short8 t;
#pragma unroll
    for (int j = 0; j < 8; ++j) t[j] = (short)xs[(cb + j) * 64 + scol];
    bx[kc] = t;
  }

  const f32x4 fz = {0.f, 0.f, 0.f, 0.f};
  for (int p = 0; p < 3; ++p) {
    const unsigned short* W = (p == 0) ? wg : ((p == 1) ? wt : wp);
    const float* bias = (p == 0) ? bg : ((p == 1) ? bt : bp);
    f32x4 acc[8];
#pragma unroll
    for (int dt = 0; dt < 8; ++dt) acc[dt] = fz;
#pragma unroll
    for (int dt = 0; dt < 8; ++dt) {
      const unsigned short* wrow = W + (size_t)(dt * 16 + l15) * C_ + g * 8;
#pragma unroll
      for (int kc = 0; kc < 8; ++kc) {
        short8 a = *reinterpret_cast<const short8*>(wrow + kc * 32);
        acc[dt] = MFMA16(a, bx[kc], acc[dt]);
      }
    }
    if (p == 0) {  // V -> (n, d, s)
#pragma unroll
      for (int dt = 0; dt < 8; ++dt) {
#pragma unroll
        for (int r = 0; r < 4; ++r) {
          int d = dt * 16 + 4 * g + r;
          vb[((size_t)n * D_ + d) * S_ + s0 + scol] = f2bf(acc[dt][r] + bias[d]);
        }
      }
    } else {       // Q/K -> (n, s, d)
      unsigned short* dst = (p == 1) ? qb : kb;
      unsigned short* row = dst + ((size_t)(n * S_) + s0 + scol) * D_;
#pragma unroll
      for (int dt = 0; dt < 8; ++dt) {
        ushort4v o;
#pragma unroll
        for (int r = 0; r < 4; ++r) o[r] = f2bf(acc[dt][r] + bias[dt * 16 + 4 * g + r]);
        *reinterpret_cast<ushort4v*>(row + dt * 16 + 4 * g) = o;
      }
    }
  }
}

// ---------------- flash attention, KV-split: each block does 16 KV tiles ----------------
// writes normalized partial y_i = O_i / l_i (bf16) + per-row (m_i, l_i) stats
__global__ __launch_bounds__(256, 4) void k_attn(
    const unsigned short* __restrict__ qb, const unsigned short* __restrict__ kb,
    const unsigned short* __restrict__ vb,
    unsigned short* __restrict__ opart, float2* __restrict__ ml)
{
  __shared__ __align__(16) unsigned short ks[64 * 128];    // [kv][d] swizzled, 16 KB
  __shared__ __align__(16) unsigned short vs[128 * 64];    // [d][kv] swizzled, 16 KB
  __shared__ __align__(16) unsigned short ps[4 * 16 * 64]; // per-wave P, 8 KB
  const int tid = threadIdx.x, lane = tid & 63, wid = tid >> 6;
  const int l15 = lane & 15, g = lane >> 4;
  const int b = blockIdx.x;
  const int sp = b & 3, qt = (b >> 2) & 63, n = b >> 8;
  const int q0 = qt << 6;

  // Q A-fragments straight from global (no LDS)
  const unsigned short* qrow = qb + ((size_t)(n * S_) + q0 + wid * 16 + l15) * D_;
  short8 aq[4];
#pragma unroll
  for (int kc = 0; kc < 4; ++kc)
    aq[kc] = *reinterpret_cast<const short8*>(qrow + kc * 32 + g * 8);

  // per-lane pre-swizzled staging source offsets (ushort units) + uniform LDS dests
  unsigned koff[4], voff[4];
  unsigned short *klp[4], *vlp[4];
#pragma unroll
  for (int j = 0; j < 4; ++j) {
    int f = j * 256 + tid;
    int kr = f >> 4, kc = f & 15;
    koff[j] = kr * D_ + ((kc ^ (kr & 7)) << 3);
    int vr = f >> 3, vc = f & 7;
    voff[j] = vr * S_ + ((vc ^ (vr & 7)) << 3);
    unsigned ub = (unsigned)(j * 256 + (tid & 192)) * 8;  // wave-uniform chunk base
    klp[j] = ks + ub;
    vlp[j] = vs + ub;
  }
  const unsigned short* kb0 = kb + ((size_t)n * S_ + (size_t)sp * TPS * 64) * D_;
  const unsigned short* vb0 = vb + (size_t)n * D_ * S_ + sp * TPS * 64;

  const f32x4 fz = {0.f, 0.f, 0.f, 0.f};
  float m_[4], l_[4];
  f32x4 acc_o[8];
#pragma unroll
  for (int r = 0; r < 4; ++r) { m_[r] = -3.4e38f; l_[r] = 0.f; }
#pragma unroll
  for (int dt = 0; dt < 8; ++dt) acc_o[dt] = fz;
  unsigned short* pw = ps + wid * 1024;

  for (int t = 0; t < TPS; ++t) {
    __syncthreads();  // all waves done reading previous tile
    const unsigned short* kt = kb0 + (size_t)t * 64 * D_;
    const unsigned short* vt = vb0 + t * 64;
#pragma unroll
    for (int j = 0; j < 4; ++j) gload16(kt + koff[j], klp[j]);
#pragma unroll
    for (int j = 0; j < 4; ++j) gload16(vt + voff[j], vlp[j]);
    __syncthreads();  // barrier implies vmcnt(0): tile resident

    // S = Q K^T
    f32x4 sc[4];
#pragma unroll
    for (int ct = 0; ct < 4; ++ct) {
      f32x4 a4 = fz;
      int r = ct * 16 + l15;
#pragma unroll
      for (int kc = 0; kc < 4; ++kc) {
        int ch = (kc * 4 + g) ^ (r & 7);
        short8 bk = *reinterpret_cast<const short8*>(ks + r * 128 + ch * 8);
        a4 = MFMA16(aq[kc], bk, a4);
      }
      sc[ct] = a4;
    }

    // online softmax with defer-max (T13, THR=8)
    float mx[4], gr = 0.f;
#pragma unroll
    for (int r = 0; r < 4; ++r) {
      mx[r] = redmax16(fmaxf(fmaxf(sc[0][r], sc[1][r]), fmaxf(sc[2][r], sc[3][r])));
      gr = fmaxf(gr, mx[r] - m_[r]);
    }
    if (!__all(gr <= 8.0f)) {
      float ss[4];
#pragma unroll
      for (int r = 0; r < 4; ++r) {
        float mn = fmaxf(m_[r], mx[r]);
        ss[r] = exp2f((m_[r] - mn) * LOG2E);
        m_[r] = mn;
        l_[r] *= ss[r];
      }
#pragma unroll
      for (int dt = 0; dt < 8; ++dt)
#pragma unroll
        for (int r = 0; r < 4; ++r) acc_o[dt][r] *= ss[r];
    }
    float rs[4] = {0.f, 0.f, 0.f, 0.f};
#pragma unroll
    for (int ct = 0; ct < 4; ++ct)
#pragma unroll
      for (int r = 0; r < 4; ++r) {
        float pv = exp2f((sc[ct][r] - m_[r]) * LOG2E);
        sc[ct][r] = pv;
        rs[r] += pv;
      }
#pragma unroll
    for (int r = 0; r < 4; ++r) l_[r] += redsum16(rs[r]);

    // P -> wave-private swizzled LDS
#pragma unroll
    for (int ct = 0; ct < 4; ++ct)
#pragma unroll
      for (int r = 0; r < 4; ++r) {
        int row = 4 * g + r;
        int col = ct * 16 + l15;
        pw[row * 64 + (col ^ ((row & 7) << 3))] = f2bf(sc[ct][r]);
      }
    asm volatile("s_waitcnt lgkmcnt(0)" ::: "memory");

    // O += P V
    short8 ap[2];
#pragma unroll
    for (int kk = 0; kk < 2; ++kk) {
      int ch = (kk * 4 + g) ^ (l15 & 7);
      ap[kk] = *reinterpret_cast<const short8*>(pw + l15 * 64 + ch * 8);
    }
#pragma unroll
    for (int dt = 0; dt < 8; ++dt) {
      int r = dt * 16 + l15;
#pragma unroll
      for (int kk = 0; kk < 2; ++kk) {
        int ch = (kk * 4 + g) ^ (r & 7);
        short8 bv = *reinterpret_cast<const short8*>(vs + r * 64 + ch * 8);
        acc_o[dt] = MFMA16(ap[kk], bv, acc_o[dt]);
      }
    }
  }

  // epilogue: normalized partial + stats
  float inv[4];
#pragma unroll
  for (int r = 0; r < 4; ++r) inv[r] = 1.f / l_[r];
  unsigned short* ob = opart + (((size_t)(n * SPLIT + sp)) * S_ + q0 + wid * 16) * D_;
#pragma unroll
  for (int dt = 0; dt < 8; ++dt)
#pragma unroll
    for (int r = 0; r < 4; ++r)
      ob[(size_t)(4 * g + r) * D_ + dt * 16 + l15] = f2bf(acc_o[dt][r] * inv[r]);
  if (l15 == 0) {
    float2* mlp = ml + ((size_t)(n * SPLIT + sp)) * S_ + q0 + wid * 16;
#pragma unroll
    for (int r = 0; r < 4; ++r) mlp[4 * g + r] = make_float2(m_[r], l_[r]);
  }
}

// ---------------- merge partials + out = Wz*y + bz + x ----------------
__global__ __launch_bounds__(256, 2) void k_final(
    const unsigned short* __restrict__ opart, const float2* __restrict__ ml,
    const unsigned short* __restrict__ wz, const float* __restrict__ bz,
    const float* __restrict__ x, float* __restrict__ out)
{
  __shared__ __align__(16) unsigned short ysm[32 * 128];  // [s][d] swizzled, 8 KB
  __shared__ float wsm[32][4];
  const int tid = threadIdx.x, lane = tid & 63, wid = tid >> 6;
  const int l15 = lane & 15, g = lane >> 4;
  const int n = blockIdx.x >> 7, s0 = (blockIdx.x & 127) << 5;

  if (tid < 32) {
    int row = s0 + tid;
    float m0, l0, m1, l1, m2, l2, m3, l3;
    { float2 v = ml[(size_t)(n * 4 + 0) * S_ + row]; m0 = v.x; l0 = v.y; }
    { float2 v = ml[(size_t)(n * 4 + 1) * S_ + row]; m1 = v.x; l1 = v.y; }
    { float2 v = ml[(size_t)(n * 4 + 2) * S_ + row]; m2 = v.x; l2 = v.y; }
    { float2 v = ml[(size_t)(n * 4 + 3) * S_ + row]; m3 = v.x; l3 = v.y; }
    float M = fmaxf(fmaxf(m0, m1), fmaxf(m2, m3));
    float w0 = l0 * exp2f((m0 - M) * LOG2E);
    float w1 = l1 * exp2f((m1 - M) * LOG2E);
    float w2 = l2 * exp2f((m2 - M) * LOG2E);
    float w3 = l3 * exp2f((m3 - M) * LOG2E);
    float L = 1.f / (w0 + w1 + w2 + w3);
    wsm[tid][0] = w0 * L; wsm[tid][1] = w1 * L;
    wsm[tid][2] = w2 * L; wsm[tid][3] = w3 * L;
  }
  __syncthreads();

  // weighted merge of 4 partials -> ysm (bf16, swizzled)
#pragma unroll
  for (int i = 0; i < 2; ++i) {
    int ch = i * 256 + tid;                 // 512 ushort8-chunks
    int row = ch >> 4, d8 = ch & 15;
    const unsigned short* p = opart + ((size_t)(n * 4) * S_ + s0 + row) * D_ + d8 * 8;
    ushort8 a0 = *reinterpret_cast<const ushort8*>(p);
    ushort8 a1 = *reinterpret_cast<const ushort8*>(p + (size_t)S_ * D_);
    ushort8 a2 = *reinterpret_cast<const ushort8*>(p + (size_t)2 * S_ * D_);
    ushort8 a3 = *reinterpret_cast<const ushort8*>(p + (size_t)3 * S_ * D_);
    float w0 = wsm[row][0], w1 = wsm[row][1], w2 = wsm[row][2], w3 = wsm[row][3];
    ushort8 o;
#pragma unroll
    for (int e = 0; e < 8; ++e) {
      float acc = bf2f(a0[e]) * w0 + bf2f(a1[e]) * w1 + bf2f(a2[e]) * w2 + bf2f(a3[e]) * w3;
      o[e] = f2bf(acc);
    }
    *reinterpret_cast<ushort8*>(ysm + row * 128 + ((d8 ^ (row & 7)) << 3)) = o;
  }
  __syncthreads();

  const int c0 = wid * 64;
  const f32x4 fz = {0.f, 0.f, 0.f, 0.f};
  f32x4 acc[4][2];
#pragma unroll
  for (int ct = 0; ct < 4; ++ct)
#pragma unroll
    for (int st = 0; st < 2; ++st) acc[ct][st] = fz;
#pragma unroll
  for (int kc = 0; kc < 4; ++kc) {
    short8 by[2];
#pragma unroll
    for (int st = 0; st < 2; ++st) {
      int r = st * 16 + l15;
      int ch = (kc * 4 + g) ^ (r & 7);
      by[st] = *reinterpret_cast<const short8*>(ysm + r * 128 + ch * 8);
    }
#pragma unroll
    for (int ct = 0; ct < 4; ++ct) {
      const short8 aw = *reinterpret_cast<const short8*>(
          wz + (size_t)(c0 + ct * 16 + l15) * D_ + kc * 32 + g * 8);
#pragma unroll
      for (int st = 0; st < 2; ++st) acc[ct][st] = MFMA16(aw, by[st], acc[ct][st]);
    }
  }
#pragma unroll
  for (int ct = 0; ct < 4; ++ct)
#pragma unroll
    for (int r = 0; r < 4; ++r) {
      int c = c0 + ct * 16 + 4 * g + r;
      float bias = bz[c];
#pragma unroll
      for (int st = 0; st < 2; ++st) {
        int s = s0 + st * 16 + l15;
        size_t idx = ((size_t)(n * C_ + c)) * S_ + s;
        out[idx] = acc[ct][st][r] + bias + x[idx];
      }
    }
}

extern "C" void kernel_launch(void* const* d_in, const int* in_sizes, int n_in,
                              void* d_out, int out_size, void* d_ws, size_t ws_size,
                              hipStream_t stream) {
  const float* x  = (const float*)d_in[0];
  const float* Wg = (const float*)d_in[1];
  const float* bg = (const float*)d_in[2];
  const float* Wt = (const float*)d_in[3];
  const float* bt = (const float*)d_in[4];
  const float* Wp = (const float*)d_in[5];
  const float* bp = (const float*)d_in[6];
  const float* Wz = (const float*)d_in[7];
  const float* bz = (const float*)d_in[8];
  float* out = (float*)d_out;
  char* ws = (char*)d_ws;
  const size_t MB = 1u << 20;
  unsigned short* qb    = (unsigned short*)(ws);                    // 4 MB (N,S,D)
  unsigned short* kb    = (unsigned short*)(ws + 4 * MB);           // 4 MB (N,S,D)
  unsigned short* vb    = (unsigned short*)(ws + 8 * MB);           // 4 MB (N,D,S)
  unsigned short* opart = (unsigned short*)(ws + 12 * MB);          // 16 MB (N*4,S,D)
  float2*        mlbuf  = (float2*)(ws + 28 * MB);                  // 512 KB
  unsigned short* wgb   = (unsigned short*)(ws + 28 * MB + 524288);
  unsigned short* wtb   = (unsigned short*)(ws + 28 * MB + 524288 + 65536);
  unsigned short* wpb   = (unsigned short*)(ws + 28 * MB + 524288 + 131072);
  unsigned short* wzb   = (unsigned short*)(ws + 28 * MB + 524288 + 196608);

  k_convw<<<64, 256, 0, stream>>>(Wg, Wt, Wp, Wz, wgb, wtb, wpb, wzb);
  k_proj <<<256, 256, 0, stream>>>(x, wgb, wtb, wpb, bg, bt, bp, qb, kb, vb);
  k_attn <<<1024, 256, 0, stream>>>(qb, kb, vb, opart, mlbuf);
  k_final<<<512, 256, 0, stream>>>(opart, mlbuf, wzb, bz, x, out);
}

// Round 3
// 113.637 us; speedup vs baseline: 1.7500x; 1.2365x over previous
//
#include <hip/hip_runtime.h>
#include <math.h>

#define N_ 4
#define C_ 256
#define D_ 128
#define S_ 4096
#define LOG2E 1.4426950408889634f
#define SPLIT 4
#define TPS 16   // KV tiles per split slice (64 total / SPLIT)

typedef __attribute__((ext_vector_type(4))) float f32x4;
typedef __attribute__((ext_vector_type(16))) float f32x16;
typedef __attribute__((ext_vector_type(8))) short short8;
typedef __attribute__((ext_vector_type(8))) unsigned short ushort8;
typedef __attribute__((ext_vector_type(4))) unsigned short ushort4v;

#define MFMA16(a, b, c) __builtin_amdgcn_mfma_f32_16x16x32_bf16((a), (b), (c), 0, 0, 0)
#define MFMA32(a, b, c) __builtin_amdgcn_mfma_f32_32x32x16_bf16((a), (b), (c), 0, 0, 0)

__device__ __forceinline__ unsigned short f2bf(float f) {
  union { float f; unsigned int u; } v; v.f = f;
  unsigned int r = v.u + 0x7fffu + ((v.u >> 16) & 1u);  // RNE
  return (unsigned short)(r >> 16);
}
__device__ __forceinline__ float bf2f(unsigned short u) {
  union { unsigned int u; float f; } v; v.u = ((unsigned int)u) << 16;
  return v.f;
}
// packed f32x2 -> bf16x2 (RNE), T12 recipe: no builtin on gfx950
__device__ __forceinline__ unsigned cvtpk(float lo, float hi) {
  unsigned r;
  asm("v_cvt_pk_bf16_f32 %0, %1, %2" : "=v"(r) : "v"(lo), "v"(hi));
  return r;
}
__device__ __forceinline__ float vmax16(const f32x16& v) {
  float a = fmaxf(fmaxf(v[0], v[1]), fmaxf(v[2], v[3]));
  float b = fmaxf(fmaxf(v[4], v[5]), fmaxf(v[6], v[7]));
  float c = fmaxf(fmaxf(v[8], v[9]), fmaxf(v[10], v[11]));
  float d = fmaxf(fmaxf(v[12], v[13]), fmaxf(v[14], v[15]));
  return fmaxf(fmaxf(a, b), fmaxf(c, d));
}
__device__ __forceinline__ float vsum16(const f32x16& v) {
  float a = (v[0] + v[1]) + (v[2] + v[3]);
  float b = (v[4] + v[5]) + (v[6] + v[7]);
  float c = (v[8] + v[9]) + (v[10] + v[11]);
  float d = (v[12] + v[13]) + (v[14] + v[15]);
  return (a + b) + (c + d);
}
// async global->LDS, 16B per lane; lds dest must be wave-uniform base (lane-linear fill)
__device__ __forceinline__ void gload16(const void* g, void* l) {
  __builtin_amdgcn_global_load_lds((const __attribute__((address_space(1))) unsigned int*)g,
                                   (__attribute__((address_space(3))) unsigned int*)l,
                                   16, 0, 0);
}

// ---------------- all 4 weight matrices fp32 -> bf16 in one launch ----------------
__global__ void k_convw(const float* __restrict__ w0, const float* __restrict__ w1,
                        const float* __restrict__ w2, const float* __restrict__ w3,
                        unsigned short* __restrict__ d0, unsigned short* __restrict__ d1,
                        unsigned short* __restrict__ d2, unsigned short* __restrict__ d3) {
  int b = blockIdx.x;
  int w = b >> 4;
  int i = (b & 15) * 256 + threadIdx.x;
  const float* s = (w == 0) ? w0 : (w == 1) ? w1 : (w == 2) ? w2 : w3;
  unsigned short* d = (w == 0) ? d0 : (w == 1) ? d1 : (w == 2) ? d2 : d3;
  const float4* sp = reinterpret_cast<const float4*>(s) + (size_t)i * 2;
  float4 a = sp[0], c = sp[1];
  ushort8 o;
  o[0] = f2bf(a.x); o[1] = f2bf(a.y); o[2] = f2bf(a.z); o[3] = f2bf(a.w);
  o[4] = f2bf(c.x); o[5] = f2bf(c.y); o[6] = f2bf(c.z); o[7] = f2bf(c.w);
  reinterpret_cast<ushort8*>(d)[i] = o;
}

// ---------------- projections: V=Wg*x -> (N,D,S), Q=Wt*x -> (N,S,D), K=Wp*x -> (N,S,D)
__global__ __launch_bounds__(256, 2) void k_proj(
    const float* __restrict__ x,
    const unsigned short* __restrict__ wg, const unsigned short* __restrict__ wt,
    const unsigned short* __restrict__ wp,
    const float* __restrict__ bg, const float* __restrict__ bt, const float* __restrict__ bp,
    unsigned short* __restrict__ qb, unsigned short* __restrict__ kb, unsigned short* __restrict__ vb)
{
  __shared__ __align__(16) unsigned short xs[C_ * 64];  // [c][s] bf16, 32 KB
  const int tid = threadIdx.x;
  const int n = blockIdx.x >> 6;
  const int s0 = (blockIdx.x & 63) << 6;
  const float* xsrc = x + (size_t)n * C_ * S_ + s0;
#pragma unroll
  for (int i = 0; i < 16; ++i) {
    int ch = i * 256 + tid;
    int c = ch >> 4, s4 = (ch & 15) << 2;
    float4 v = *reinterpret_cast<const float4*>(xsrc + (size_t)c * S_ + s4);
    ushort4v o;
    o[0] = f2bf(v.x); o[1] = f2bf(v.y); o[2] = f2bf(v.z); o[3] = f2bf(v.w);
    *reinterpret_cast<ushort4v*>(xs + c * 64 + s4) = o;
  }
  __syncthreads();
  const int lane = tid & 63, wid = tid >> 6;
  const int l15 = lane & 15, g = lane >> 4;
  const int scol = wid * 16 + l15;

  short8 bx[8];
#pragma unroll
  for (int kc = 0; kc < 8; ++kc) {
    int cb = kc * 32 + g * 8;
    short8 t;
#pragma unroll
    for (int j = 0; j < 8; ++j) t[j] = (short)xs[(cb + j) * 64 + scol];
    bx[kc] = t;
  }

  const f32x4 fz = {0.f, 0.f, 0.f, 0.f};
  for (int p = 0; p < 3; ++p) {
    const unsigned short* W = (p == 0) ? wg : ((p == 1) ? wt : wp);
    const float* bias = (p == 0) ? bg : ((p == 1) ? bt : bp);
    f32x4 acc[8];
#pragma unroll
    for (int dt = 0; dt < 8; ++dt) acc[dt] = fz;
#pragma unroll
    for (int dt = 0; dt < 8; ++dt) {
      const unsigned short* wrow = W + (size_t)(dt * 16 + l15) * C_ + g * 8;
#pragma unroll
      for (int kc = 0; kc < 8; ++kc) {
        short8 a = *reinterpret_cast<const short8*>(wrow + kc * 32);
        acc[dt] = MFMA16(a, bx[kc], acc[dt]);
      }
    }
    if (p == 0) {  // V -> (n, d, s)
#pragma unroll
      for (int dt = 0; dt < 8; ++dt) {
#pragma unroll
        for (int r = 0; r < 4; ++r) {
          int d = dt * 16 + 4 * g + r;
          vb[((size_t)n * D_ + d) * S_ + s0 + scol] = f2bf(acc[dt][r] + bias[d]);
        }
      }
    } else {       // Q/K -> (n, s, d)
      unsigned short* dst = (p == 1) ? qb : kb;
      unsigned short* row = dst + ((size_t)(n * S_) + s0 + scol) * D_;
#pragma unroll
      for (int dt = 0; dt < 8; ++dt) {
        ushort4v o;
#pragma unroll
        for (int r = 0; r < 4; ++r) o[r] = f2bf(acc[dt][r] + bias[dt * 16 + 4 * g + r]);
        *reinterpret_cast<ushort4v*>(row + dt * 16 + 4 * g) = o;
      }
    }
  }
}

// ---------------- flash attention, swapped-QK^T 32x32, in-register softmax ----------------
// 4 waves x 32 q-rows = 128 q/block; KVBLK=64 double-buffered; KV-split x4
__global__ __launch_bounds__(256, 2) void k_attn(
    const unsigned short* __restrict__ qb, const unsigned short* __restrict__ kb,
    const unsigned short* __restrict__ vb,
    unsigned short* __restrict__ opart, float2* __restrict__ ml)
{
  __shared__ __align__(16) unsigned short ksm[2][64 * 128];  // [kv][d] swizzled, 2x16KB
  __shared__ __align__(16) unsigned short vsm[2][128 * 64];  // [d][kv] swizzled, 2x16KB
  const int tid = threadIdx.x, lane = tid & 63, w = tid >> 6;
  const int l31 = lane & 31, hi = lane >> 5;
  const int b = blockIdx.x;
  const int sp = b & 3, qt = (b >> 2) & 31, n = b >> 7;
  const int q0 = qt << 7;

  // staging offsets: pre-swizzled global source, linear LDS dest (involution on read)
  unsigned koff[4], voff[4], ubo[4];
#pragma unroll
  for (int j = 0; j < 4; ++j) {
    int f = j * 256 + tid;
    int kr = f >> 4, kc = f & 15;
    koff[j] = kr * D_ + ((kc ^ (kr & 7)) << 3);
    int vr = f >> 3, vc = f & 7;
    voff[j] = vr * S_ + ((vc ^ (vr & 7)) << 3);
    ubo[j] = (unsigned)(j * 256 + (tid & 192)) * 8;  // wave-uniform chunk base (ushorts)
  }
  const unsigned short* kb0 = kb + ((size_t)n * S_ + (size_t)sp * TPS * 64) * D_;
  const unsigned short* vb0 = vb + (size_t)n * D_ * S_ + sp * TPS * 64;

  auto stage = [&](int buf, int t) {
    const unsigned short* kt = kb0 + (size_t)t * 64 * D_;
    const unsigned short* vt = vb0 + t * 64;
#pragma unroll
    for (int j = 0; j < 4; ++j) gload16(kt + koff[j], &ksm[buf][ubo[j]]);
#pragma unroll
    for (int j = 0; j < 4; ++j) gload16(vt + voff[j], &vsm[buf][ubo[j]]);
  };

  stage(0, 0);

  // Q B-fragments (hoisted): lane holds Q[q=l31][d = kstep*16 + hi*8 .. +8]
  const unsigned short* qsrc = qb + ((size_t)(n * S_) + q0 + w * 32 + l31) * D_;
  short8 qf[8];
#pragma unroll
  for (int k = 0; k < 8; ++k)
    qf[k] = *reinterpret_cast<const short8*>(qsrc + k * 16 + hi * 8);

  const f32x16 z16 = {0.f,0.f,0.f,0.f,0.f,0.f,0.f,0.f,0.f,0.f,0.f,0.f,0.f,0.f,0.f,0.f};
  f32x16 oacc[4];
#pragma unroll
  for (int db = 0; db < 4; ++db) oacc[db] = z16;
  float m_ = -3.4e38f, l_ = 0.f;

  __syncthreads();  // tile 0 resident (barrier drains vmcnt)
  int cur = 0;

  for (int t = 0; t < TPS; ++t) {
    if (t + 1 < TPS) stage(cur ^ 1, t + 1);  // async prefetch across compute

    const unsigned short* ksb = ksm[cur];
    const unsigned short* vsb = vsm[cur];

    // S^T = K Q : lane holds S[kv = kvb*32 + rr(reg,hi)][q = l31]
    f32x16 pA = z16, pB = z16;
    __builtin_amdgcn_s_setprio(1);
#pragma unroll
    for (int ks = 0; ks < 8; ++ks) {
      int c = ks * 2 + hi;
      int r0 = l31, r1 = 32 + l31;
      short8 k0 = *reinterpret_cast<const short8*>(ksb + r0 * 128 + ((c ^ (r0 & 7)) << 3));
      short8 k1 = *reinterpret_cast<const short8*>(ksb + r1 * 128 + ((c ^ (r1 & 7)) << 3));
      pA = MFMA32(k0, qf[ks], pA);
      pB = MFMA32(k1, qf[ks], pB);
    }
    __builtin_amdgcn_s_setprio(0);

    // online softmax, fully in-register (q = l31 per lane; partner lane^32 has other kv half)
    float mrow = fmaxf(vmax16(pA), vmax16(pB));
    mrow = fmaxf(mrow, __shfl_xor(mrow, 32));
    if (!__all(mrow - m_ <= 8.0f)) {   // T13 defer-max
      float mn = fmaxf(m_, mrow);
      float ss = exp2f((m_ - mn) * LOG2E);
      m_ = mn; l_ *= ss;
#pragma unroll
      for (int reg = 0; reg < 16; ++reg) {
        int rr = (reg & 3) + 8 * (reg >> 2) + 4 * hi;
        float sb = __shfl(ss, rr);   // broadcast to O-layout rows
#pragma unroll
        for (int db = 0; db < 4; ++db) oacc[db][reg] *= sb;
      }
    }
#pragma unroll
    for (int i = 0; i < 16; ++i) pA[i] = exp2f((pA[i] - m_) * LOG2E);
#pragma unroll
    for (int i = 0; i < 16; ++i) pB[i] = exp2f((pB[i] - m_) * LOG2E);
    float rs = vsum16(pA) + vsum16(pB);
    l_ += rs + __shfl_xor(rs, 32);

    // P -> bf16 A-fragments via cvt_pk + lane^32 exchange (T12)
    short8 pa[4];
#pragma unroll
    for (int ks = 0; ks < 4; ++ks) {
      const f32x16& p = (ks < 2) ? pA : pB;
      int ba = (ks & 1) * 8;          // regs 4*r3a .. +3, r3a=(ks&1)*2
      unsigned ua0 = cvtpk(p[ba + 0], p[ba + 1]);
      unsigned ua1 = cvtpk(p[ba + 2], p[ba + 3]);
      unsigned ub0 = cvtpk(p[ba + 4], p[ba + 5]);
      unsigned ub1 = cvtpk(p[ba + 6], p[ba + 7]);
      unsigned x0 = (unsigned)__shfl_xor((int)(hi ? ua0 : ub0), 32);
      unsigned x1 = (unsigned)__shfl_xor((int)(hi ? ua1 : ub1), 32);
      union { unsigned u[4]; short8 s; } m;
      m.u[0] = hi ? x0 : ua0;  m.u[1] = hi ? x1 : ua1;
      m.u[2] = hi ? ub0 : x0;  m.u[3] = hi ? ub1 : x1;
      pa[ks] = m.s;
    }

    // O += P V : oacc[db] holds O[q = rr(reg,hi)][d = db*32 + l31]
    __builtin_amdgcn_s_setprio(1);
#pragma unroll
    for (int ks = 0; ks < 4; ++ks) {
      int c = ks * 2 + hi;
#pragma unroll
      for (int db = 0; db < 4; ++db) {
        int r = db * 32 + l31;
        short8 v = *reinterpret_cast<const short8*>(vsb + r * 64 + ((c ^ (r & 7)) << 3));
        oacc[db] = MFMA32(pa[ks], v, oacc[db]);
      }
    }
    __builtin_amdgcn_s_setprio(0);

    __syncthreads();  // next tile resident; all waves done with cur
    cur ^= 1;
  }

  // epilogue: normalized partial + stats
  float linv = 1.f / l_;
  unsigned short* ob = opart + (((size_t)(n * SPLIT + sp)) * S_ + q0 + w * 32) * D_;
#pragma unroll
  for (int reg = 0; reg < 16; ++reg) {
    int rr = (reg & 3) + 8 * (reg >> 2) + 4 * hi;
    float li = __shfl(linv, rr);
#pragma unroll
    for (int db = 0; db < 4; ++db)
      ob[(size_t)rr * D_ + db * 32 + l31] = f2bf(oacc[db][reg] * li);
  }
  if (hi == 0) {
    ml[((size_t)(n * SPLIT + sp)) * S_ + q0 + w * 32 + l31] = make_float2(m_, l_);
  }
}

// ---------------- merge partials + out = Wz*y + bz + x ----------------
__global__ __launch_bounds__(256, 2) void k_final(
    const unsigned short* __restrict__ opart, const float2* __restrict__ ml,
    const unsigned short* __restrict__ wz, const float* __restrict__ bz,
    const float* __restrict__ x, float* __restrict__ out)
{
  __shared__ __align__(16) unsigned short ysm[32 * 128];  // [s][d] swizzled, 8 KB
  __shared__ float wsm[32][4];
  const int tid = threadIdx.x, lane = tid & 63, wid = tid >> 6;
  const int l15 = lane & 15, g = lane >> 4;
  const int n = blockIdx.x >> 7, s0 = (blockIdx.x & 127) << 5;

  if (tid < 32) {
    int row = s0 + tid;
    float m0, l0, m1, l1, m2, l2, m3, l3;
    { float2 v = ml[(size_t)(n * 4 + 0) * S_ + row]; m0 = v.x; l0 = v.y; }
    { float2 v = ml[(size_t)(n * 4 + 1) * S_ + row]; m1 = v.x; l1 = v.y; }
    { float2 v = ml[(size_t)(n * 4 + 2) * S_ + row]; m2 = v.x; l2 = v.y; }
    { float2 v = ml[(size_t)(n * 4 + 3) * S_ + row]; m3 = v.x; l3 = v.y; }
    float M = fmaxf(fmaxf(m0, m1), fmaxf(m2, m3));
    float w0 = l0 * exp2f((m0 - M) * LOG2E);
    float w1 = l1 * exp2f((m1 - M) * LOG2E);
    float w2 = l2 * exp2f((m2 - M) * LOG2E);
    float w3 = l3 * exp2f((m3 - M) * LOG2E);
    float L = 1.f / (w0 + w1 + w2 + w3);
    wsm[tid][0] = w0 * L; wsm[tid][1] = w1 * L;
    wsm[tid][2] = w2 * L; wsm[tid][3] = w3 * L;
  }
  __syncthreads();

#pragma unroll
  for (int i = 0; i < 2; ++i) {
    int ch = i * 256 + tid;
    int row = ch >> 4, d8 = ch & 15;
    const unsigned short* p = opart + ((size_t)(n * 4) * S_ + s0 + row) * D_ + d8 * 8;
    ushort8 a0 = *reinterpret_cast<const ushort8*>(p);
    ushort8 a1 = *reinterpret_cast<const ushort8*>(p + (size_t)S_ * D_);
    ushort8 a2 = *reinterpret_cast<const ushort8*>(p + (size_t)2 * S_ * D_);
    ushort8 a3 = *reinterpret_cast<const ushort8*>(p + (size_t)3 * S_ * D_);
    float w0 = wsm[row][0], w1 = wsm[row][1], w2 = wsm[row][2], w3 = wsm[row][3];
    ushort8 o;
#pragma unroll
    for (int e = 0; e < 8; ++e) {
      float acc = bf2f(a0[e]) * w0 + bf2f(a1[e]) * w1 + bf2f(a2[e]) * w2 + bf2f(a3[e]) * w3;
      o[e] = f2bf(acc);
    }
    *reinterpret_cast<ushort8*>(ysm + row * 128 + ((d8 ^ (row & 7)) << 3)) = o;
  }
  __syncthreads();

  const int c0 = wid * 64;
  const f32x4 fz = {0.f, 0.f, 0.f, 0.f};
  f32x4 acc[4][2];
#pragma unroll
  for (int ct = 0; ct < 4; ++ct)
#pragma unroll
    for (int st = 0; st < 2; ++st) acc[ct][st] = fz;
#pragma unroll
  for (int kc = 0; kc < 4; ++kc) {
    short8 by[2];
#pragma unroll
    for (int st = 0; st < 2; ++st) {
      int r = st * 16 + l15;
      int ch = (kc * 4 + g) ^ (r & 7);
      by[st] = *reinterpret_cast<const short8*>(ysm + r * 128 + ch * 8);
    }
#pragma unroll
    for (int ct = 0; ct < 4; ++ct) {
      const short8 aw = *reinterpret_cast<const short8*>(
          wz + (size_t)(c0 + ct * 16 + l15) * D_ + kc * 32 + g * 8);
#pragma unroll
      for (int st = 0; st < 2; ++st) acc[ct][st] = MFMA16(aw, by[st], acc[ct][st]);
    }
  }
#pragma unroll
  for (int ct = 0; ct < 4; ++ct)
#pragma unroll
    for (int r = 0; r < 4; ++r) {
      int c = c0 + ct * 16 + 4 * g + r;
      float bias = bz[c];
#pragma unroll
      for (int st = 0; st < 2; ++st) {
        int s = s0 + st * 16 + l15;
        size_t idx = ((size_t)(n * C_ + c)) * S_ + s;
        out[idx] = acc[ct][st][r] + bias + x[idx];
      }
    }
}

extern "C" void kernel_launch(void* const* d_in, const int* in_sizes, int n_in,
                              void* d_out, int out_size, void* d_ws, size_t ws_size,
                              hipStream_t stream) {
  const float* x  = (const float*)d_in[0];
  const float* Wg = (const float*)d_in[1];
  const float* bg = (const float*)d_in[2];
  const float* Wt = (const float*)d_in[3];
  const float* bt = (const float*)d_in[4];
  const float* Wp = (const float*)d_in[5];
  const float* bp = (const float*)d_in[6];
  const float* Wz = (const float*)d_in[7];
  const float* bz = (const float*)d_in[8];
  float* out = (float*)d_out;
  char* ws = (char*)d_ws;
  const size_t MB = 1u << 20;
  unsigned short* qb    = (unsigned short*)(ws);                    // 4 MB (N,S,D)
  unsigned short* kb    = (unsigned short*)(ws + 4 * MB);           // 4 MB (N,S,D)
  unsigned short* vb    = (unsigned short*)(ws + 8 * MB);           // 4 MB (N,D,S)
  unsigned short* opart = (unsigned short*)(ws + 12 * MB);          // 16 MB (N*4,S,D)
  float2*        mlbuf  = (float2*)(ws + 28 * MB);                  // 512 KB
  unsigned short* wgb   = (unsigned short*)(ws + 28 * MB + 524288);
  unsigned short* wtb   = (unsigned short*)(ws + 28 * MB + 524288 + 65536);
  unsigned short* wpb   = (unsigned short*)(ws + 28 * MB + 524288 + 131072);
  unsigned short* wzb   = (unsigned short*)(ws + 28 * MB + 524288 + 196608);

  k_convw<<<64, 256, 0, stream>>>(Wg, Wt, Wp, Wz, wgb, wtb, wpb, wzb);
  k_proj <<<256, 256, 0, stream>>>(x, wgb, wtb, wpb, bg, bt, bp, qb, kb, vb);
  k_attn <<<512, 256, 0, stream>>>(qb, kb, vb, opart, mlbuf);
  k_final<<<512, 256, 0, stream>>>(opart, mlbuf, wzb, bz, x, out);
}